// Round 3
// baseline (380.133 us; speedup 1.0000x reference)
//
#include <hip/hip_runtime.h>
#include <stdint.h>

#define NPTS 8192
#define DIM  512
#define ODIM 512

typedef __attribute__((ext_vector_type(8))) short short8;
typedef __attribute__((ext_vector_type(4))) float f32x4;

__device__ __forceinline__ void gload_lds16(const void* g, void* l) {
  __builtin_amdgcn_global_load_lds(
      (__attribute__((address_space(1))) void*)g,
      (__attribute__((address_space(3))) void*)l, 16, 0, 0);
}

// round-to-nearest-even f32 -> bf16 bits (values are finite here)
__device__ __forceinline__ short f2bf(float f) {
  uint32_t u = __float_as_uint(f);
  u = (u + 0x7FFFu + ((u >> 16) & 1u)) >> 16;
  return (short)u;
}

// barrier that keeps up to N global_load_lds in flight (counted vmcnt, T4).
// sched_barrier(0) + "memory" clobber fence both IR and MI schedulers (rule 18).
#define VMB(N) do {                                          \
    asm volatile("s_waitcnt vmcnt(" #N ")" ::: "memory");    \
    __builtin_amdgcn_sched_barrier(0);                       \
    __builtin_amdgcn_s_barrier();                            \
    __builtin_amdgcn_sched_barrier(0);                       \
  } while (0)

#define BARRIER_ONLY() do {                                  \
    asm volatile("" ::: "memory");                           \
    __builtin_amdgcn_sched_barrier(0);                       \
    __builtin_amdgcn_s_barrier();                            \
    __builtin_amdgcn_sched_barrier(0);                       \
  } while (0)

// ---------------------------------------------------------------------------
// 256x256 tile NT GEMM core: BK=32, 4 LDS slots (4 x 32 KiB), 3-deep prefetch
// with counted vmcnt. 8 waves (2M x 4N), per-wave output 128x64.
// Race-freedom by slot disjointness: compute(t) reads slot t&3; stage(t+3)
// writes slot (t+3)&3 == (t-1)&3, whose last reads finished before the
// trailing barrier of iteration t-1 (program-order before this stage issue).
// LDS layout swizzle (T2): 16-B chunk index ^= (row&3)^((row>>2)&3), applied
// on the global SOURCE of global_load_lds (linear LDS dest, rule 21) and on
// the ds_read address (same involution) -> b128 reads hit the 8-cycle floor.
// ---------------------------------------------------------------------------
__device__ __forceinline__ void gemm256_pipe(const short* __restrict__ A,
                                             const short* __restrict__ B,
                                             int K, int lda, int ldb,
                                             short* lds, f32x4 acc[8][4]) {
  const int tid = threadIdx.x, wid = tid >> 6, lane = tid & 63;
  const int wr = wid >> 2, wc = wid & 3, fr = lane & 15, fg = (lane >> 4) & 3;
  const int nt = K >> 5;

  // staging context: per sweep s, this thread fetches the 16-B chunk that
  // belongs at LDS byte (wid*2+s)*1024 + lane*16 of the slot (linear dest).
  const short* ga[2]; const short* gb[2]; int dl[2];
#pragma unroll
  for (int s = 0; s < 2; ++s) {
    const int row = (wid * 2 + s) * 16 + (lane >> 2);
    const int ch  = (lane & 3) ^ ((row & 3) ^ ((row >> 2) & 3));
    ga[s] = A + (size_t)row * lda + ch * 8;
    gb[s] = B + (size_t)row * ldb + ch * 8;
    dl[s] = (wid * 2 + s) * 512;          // shorts
  }
  auto stage = [&](int t) {
    short* slot = lds + (t & 3) * 16384;
    const int k0 = t << 5;
#pragma unroll
    for (int s = 0; s < 2; ++s) gload_lds16(ga[s] + k0, slot + dl[s]);
#pragma unroll
    for (int s = 0; s < 2; ++s) gload_lds16(gb[s] + k0, slot + 8192 + dl[s]);
  };

  auto compute = [&](int t) {
    const short* sA = lds + (t & 3) * 16384;
    const short* sB = sA + 8192;
    short8 af[8], bb[4];
#pragma unroll
    for (int m = 0; m < 8; ++m) {
      const int r = wr * 128 + m * 16 + fr;
      const int c = fg ^ ((r & 3) ^ ((r >> 2) & 3));
      af[m] = *(const short8*)(sA + r * 32 + c * 8);
    }
#pragma unroll
    for (int n = 0; n < 4; ++n) {
      const int r = wc * 64 + n * 16 + fr;
      const int c = fg ^ ((r & 3) ^ ((r >> 2) & 3));
      bb[n] = *(const short8*)(sB + r * 32 + c * 8);
    }
    __builtin_amdgcn_s_setprio(1);
#pragma unroll
    for (int m = 0; m < 8; ++m)
#pragma unroll
      for (int n = 0; n < 4; ++n)
        acc[m][n] = __builtin_amdgcn_mfma_f32_16x16x32_bf16(af[m], bb[n], acc[m][n], 0, 0, 0);
    __builtin_amdgcn_s_setprio(0);
  };

  stage(0); stage(1); stage(2);           // 3-deep prologue (nt >= 4 in all uses)
  for (int t = 0; t < nt; ++t) {
    if (t + 3 < nt) stage(t + 3);         // slot (t-1)&3 — provably quiescent
    const int rem = nt - 1 - t;           // stages allowed to stay in flight
    if (rem >= 3)      VMB(12);           // 3 stages x 4 loads
    else if (rem == 2) VMB(8);
    else if (rem == 1) VMB(4);
    else               VMB(0);
    compute(t);
    BARRIER_ONLY();                       // reads of slot t&3 done block-wide
  }
}

#define ZERO_ACC8(acc)                       \
  {                                          \
    f32x4 _z = {0.f, 0.f, 0.f, 0.f};         \
    _Pragma("unroll")                        \
    for (int m = 0; m < 8; ++m)              \
      _Pragma("unroll")                      \
      for (int n = 0; n < 4; ++n) acc[m][n] = _z; \
  }

// XCD-aware swizzle of the flattened 2D block index (T1); bijective since
// all our x*y grids are multiples of 8.
__device__ __forceinline__ void xcd_swizzle(int& bx, int& by) {
  const int gx = gridDim.x, nxy = gx * gridDim.y;
  int orig = by * gx + bx;
  if ((nxy & 7) == 0) {
    const int cpx = nxy >> 3;
    orig = (orig & 7) * cpx + (orig >> 3);
  }
  bx = orig % gx; by = orig / gx;
}

// ---------------------------------------------------------------------------
// legacy 128x128 core (kept for the small YbT GEMM)
// ---------------------------------------------------------------------------
__device__ __forceinline__ void gemm_core_nt(const short* __restrict__ A,
                                             const short* __restrict__ B,
                                             int K, int lda, int ldb,
                                             short* smem, f32x4 acc[4][4]) {
  const int tid  = threadIdx.x;
  const int wid  = tid >> 6;
  const int lane = tid & 63;
  const int wr = wid >> 1, wc = wid & 1;
  const int sr = lane >> 2;
  const int sc = (lane & 3) << 3;
  const int fr = lane & 15, fg = lane >> 4;
  short* sA = smem;
  short* sB = smem + 4096;
  short* dA0 = sA + wid * 512;
  short* dA1 = sA + 2048 + wid * 512;
  short* dB0 = sB + wid * 512;
  short* dB1 = sB + 2048 + wid * 512;
  const short* pa0 = A + (size_t)(wid * 16 + sr) * lda + sc;
  const short* pa1 = A + (size_t)(64 + wid * 16 + sr) * lda + sc;
  const short* pb0 = B + (size_t)(wid * 16 + sr) * ldb + sc;
  const short* pb1 = B + (size_t)(64 + wid * 16 + sr) * ldb + sc;

  for (int k0 = 0; k0 < K; k0 += 32) {
    gload_lds16(pa0 + k0, dA0);
    gload_lds16(pa1 + k0, dA1);
    gload_lds16(pb0 + k0, dB0);
    gload_lds16(pb1 + k0, dB1);
    __syncthreads();
    short8 af[4], bb[4];
#pragma unroll
    for (int m = 0; m < 4; ++m)
      af[m] = *(const short8*)(sA + (wr * 64 + m * 16 + fr) * 32 + fg * 8);
#pragma unroll
    for (int n = 0; n < 4; ++n)
      bb[n] = *(const short8*)(sB + (wc * 64 + n * 16 + fr) * 32 + fg * 8);
#pragma unroll
    for (int m = 0; m < 4; ++m)
#pragma unroll
      for (int n = 0; n < 4; ++n)
        acc[m][n] = __builtin_amdgcn_mfma_f32_16x16x32_bf16(af[m], bb[n], acc[m][n], 0, 0, 0);
    __syncthreads();
  }
}

#define ZERO_ACC4(acc)                       \
  {                                          \
    f32x4 _z = {0.f, 0.f, 0.f, 0.f};         \
    _Pragma("unroll")                        \
    for (int m = 0; m < 4; ++m)              \
      _Pragma("unroll")                      \
      for (int n = 0; n < 4; ++n) acc[m][n] = _z; \
  }

// K1: x (f32) -> xb (bf16), sq[i] = sum x[i]^2. One wave per row.
__global__ __launch_bounds__(256) void k_prep_x(const float* __restrict__ x,
                                                short* __restrict__ xb,
                                                float* __restrict__ sq) {
  const int row  = blockIdx.x * 4 + (threadIdx.x >> 6);
  const int lane = threadIdx.x & 63;
  const float* px = x + (size_t)row * DIM + lane * 8;
  const float4 v0 = *(const float4*)px;
  const float4 v1 = *(const float4*)(px + 4);
  float s = v0.x*v0.x + v0.y*v0.y + v0.z*v0.z + v0.w*v0.w +
            v1.x*v1.x + v1.y*v1.y + v1.z*v1.z + v1.w*v1.w;
  short8 o;
  o[0]=f2bf(v0.x); o[1]=f2bf(v0.y); o[2]=f2bf(v0.z); o[3]=f2bf(v0.w);
  o[4]=f2bf(v1.x); o[5]=f2bf(v1.y); o[6]=f2bf(v1.z); o[7]=f2bf(v1.w);
  *(short8*)(xb + (size_t)row * DIM + lane * 8) = o;
#pragma unroll
  for (int m = 32; m >= 1; m >>= 1) s += __shfl_xor(s, m);
  if (lane == 0) sq[row] = s;
}

// K1b: W (f32) -> Wb (bf16)
__global__ __launch_bounds__(256) void k_prep_w(const float* __restrict__ W,
                                                short* __restrict__ Wb) {
  const int idx = blockIdx.x * 256 + threadIdx.x;
  const float4 v0 = *(const float4*)(W + (size_t)idx * 8);
  const float4 v1 = *(const float4*)(W + (size_t)idx * 8 + 4);
  short8 o;
  o[0]=f2bf(v0.x); o[1]=f2bf(v0.y); o[2]=f2bf(v0.z); o[3]=f2bf(v0.w);
  o[4]=f2bf(v1.x); o[5]=f2bf(v1.y); o[6]=f2bf(v1.z); o[7]=f2bf(v1.w);
  *(short8*)(Wb + (size_t)idx * 8) = o;
}

// K2: YbT[o][i] = bf16( sum_d Wb[o][d] * xb[i][d] )  (Y = x@W.T, transposed)
__global__ __launch_bounds__(256) void k_ybt(const short* __restrict__ xb,
                                             const short* __restrict__ Wb,
                                             short* __restrict__ YbT) {
  __shared__ short smem[8192];
  f32x4 acc[4][4];
  ZERO_ACC4(acc);
  const int rowBase = blockIdx.y * 128;  // o
  const int colBase = blockIdx.x * 128;  // i
  gemm_core_nt(Wb + (size_t)rowBase * DIM, xb + (size_t)colBase * DIM,
               DIM, DIM, DIM, smem, acc);
  const int lane = threadIdx.x & 63, wid = threadIdx.x >> 6;
  const int wr = wid >> 1, wc = wid & 1, fr = lane & 15, fg = lane >> 4;
#pragma unroll
  for (int m = 0; m < 4; ++m)
#pragma unroll
    for (int n = 0; n < 4; ++n)
#pragma unroll
      for (int r = 0; r < 4; ++r) {
        const int ro = rowBase + wr * 64 + m * 16 + fg * 4 + r;
        const int ci = colBase + wc * 64 + n * 16 + fr;
        YbT[(size_t)ro * NPTS + ci] = f2bf(acc[m][n][r]);
      }
}

// K3 (pipelined 256^2): P[i][j] = bf16(exp(min(2*dot - si - sj,0)/2048)), rowsum +=
__global__ __launch_bounds__(512, 2) void k_pmat(const short* __restrict__ xb,
                                                 const float* __restrict__ sq,
                                                 short* __restrict__ P,
                                                 float* __restrict__ rowsum,
                                                 int jbase, int SW) {
  __shared__ short lds[65536];   // 128 KiB = 4 slots x 32 KiB
  f32x4 acc[8][4];
  ZERO_ACC8(acc);
  int bx = blockIdx.x, by = blockIdx.y;
  xcd_swizzle(bx, by);
  const int rowBase = by * 256;      // i
  const int colTile = bx * 256;      // j within strip
  const int jglob = jbase + colTile;
  gemm256_pipe(xb + (size_t)rowBase * DIM, xb + (size_t)jglob * DIM,
               DIM, DIM, DIM, lds, acc);
  const int lane = threadIdx.x & 63, wid = threadIdx.x >> 6;
  const int wr = wid >> 2, wc = wid & 3, fr = lane & 15, fg = lane >> 4;
  float sj[4];
#pragma unroll
  for (int n = 0; n < 4; ++n) sj[n] = sq[jglob + wc * 64 + n * 16 + fr];
#pragma unroll
  for (int m = 0; m < 8; ++m) {
#pragma unroll
    for (int r = 0; r < 4; ++r) {
      const int i = rowBase + wr * 128 + m * 16 + fg * 4 + r;
      const float si = sq[i];
      float rs = 0.f;
#pragma unroll
      for (int n = 0; n < 4; ++n) {
        const float t = fminf(2.f * acc[m][n][r] - si - sj[n], 0.f) * (1.0f / 2048.0f);
        const float w = __expf(t);
        rs += w;
        P[(size_t)i * SW + (colTile + wc * 64 + n * 16 + fr)] = f2bf(w);
      }
      rs += __shfl_xor(rs, 1);
      rs += __shfl_xor(rs, 2);
      rs += __shfl_xor(rs, 4);
      rs += __shfl_xor(rs, 8);
      if (fr == 0) atomicAdd(&rowsum[i], rs);
    }
  }
}

// K4 (pipelined 256^2): out_acc[i][o] += sum_j P[i][j] * YbT[o][j]  (z = K-split)
__global__ __launch_bounds__(512, 2) void k_pv(const short* __restrict__ P,
                                               const short* __restrict__ YbT,
                                               float* __restrict__ out_acc,
                                               int jbase, int SW, int klen) {
  __shared__ short lds[65536];   // 128 KiB = 4 slots x 32 KiB
  f32x4 acc[8][4];
  ZERO_ACC8(acc);
  int bx = blockIdx.x, by = blockIdx.y;
  xcd_swizzle(bx, by);
  const int rowBase = by * 256;  // i
  const int colBase = bx * 256;  // o
  const int kz = blockIdx.z * klen;
  gemm256_pipe(P + (size_t)rowBase * SW + kz,
               YbT + (size_t)colBase * NPTS + jbase + kz,
               klen, SW, NPTS, lds, acc);
  const int lane = threadIdx.x & 63, wid = threadIdx.x >> 6;
  const int wr = wid >> 2, wc = wid & 3, fr = lane & 15, fg = lane >> 4;
#pragma unroll
  for (int m = 0; m < 8; ++m)
#pragma unroll
    for (int n = 0; n < 4; ++n)
#pragma unroll
      for (int r = 0; r < 4; ++r) {
        const int i = rowBase + wr * 128 + m * 16 + fg * 4 + r;
        const int o = colBase + wc * 64 + n * 16 + fr;
        atomicAdd(&out_acc[(size_t)i * ODIM + o], acc[m][n][r]);
      }
}

// K5: out = out_acc / (rowsum + eps) + b
__global__ __launch_bounds__(256) void k_final(const float* __restrict__ out_acc,
                                               const float* __restrict__ rowsum,
                                               const float* __restrict__ bvec,
                                               float* __restrict__ out) {
  const int idx = blockIdx.x * 256 + threadIdx.x;
  const int i = idx >> 7;
  const int o = (idx & 127) << 2;
  const float inv = 1.f / (rowsum[i] + 1e-8f);
  const float4 a = *(const float4*)(out_acc + (size_t)i * ODIM + o);
  const float4 bb = *(const float4*)(bvec + o);
  float4 r;
  r.x = a.x * inv + bb.x;
  r.y = a.y * inv + bb.y;
  r.z = a.z * inv + bb.z;
  r.w = a.w * inv + bb.w;
  *(float4*)(out + (size_t)i * ODIM + o) = r;
}

extern "C" void kernel_launch(void* const* d_in, const int* in_sizes, int n_in,
                              void* d_out, int out_size, void* d_ws, size_t ws_size,
                              hipStream_t stream) {
  (void)in_sizes; (void)n_in; (void)out_size;
  const float* x = (const float*)d_in[0];
  const float* W = (const float*)d_in[1];
  const float* bvec = (const float*)d_in[2];
  float* out = (float*)d_out;
  char* ws = (char*)d_ws;

  // workspace carving (bytes)
  short* xb      = (short*)(ws + 0);                  //  8 MiB
  short* Wb      = (short*)(ws + 8388608);            //  0.5 MiB
  short* YbT     = (short*)(ws + 8912896);            //  8 MiB
  float* sq      = (float*)(ws + 17301504);           //  32 KiB
  float* rowsum  = (float*)(ws + 17334272);           //  32 KiB
  float* out_acc = (float*)(ws + 17367040);           //  16 MiB
  short* P       = (short*)(ws + 34144256);           //  up to 128 MiB

  // adaptive P-strip width so everything fits in ws (multiples of 256)
  size_t pav = ws_size > 34144256 ? ws_size - 34144256 : 0;
  int SW = 8192;
  while (SW > 256 && (size_t)NPTS * SW * 2 > pav) SW >>= 1;
  const int nstrips = NPTS / SW;
  int ksplit = SW / 2048;
  if (ksplit < 1) ksplit = 1;
  if (ksplit > 4) ksplit = 4;
  const int klen = SW / ksplit;

  hipMemsetAsync(rowsum, 0, NPTS * sizeof(float), stream);
  hipMemsetAsync(out_acc, 0, (size_t)NPTS * ODIM * sizeof(float), stream);

  k_prep_x<<<dim3(NPTS / 4), 256, 0, stream>>>(x, xb, sq);
  k_prep_w<<<dim3(ODIM * DIM / 8 / 256), 256, 0, stream>>>(W, Wb);
  k_ybt<<<dim3(NPTS / 128, ODIM / 128), 256, 0, stream>>>(xb, Wb, YbT);

  for (int s = 0; s < nstrips; ++s) {
    const int jbase = s * SW;
    k_pmat<<<dim3(SW / 256, NPTS / 256), 512, 0, stream>>>(xb, sq, P, rowsum, jbase, SW);
    k_pv<<<dim3(ODIM / 256, NPTS / 256, ksplit), 512, 0, stream>>>(P, YbT, out_acc, jbase, SW, klen);
  }

  k_final<<<dim3(NPTS * ODIM / 4 / 256), 256, 0, stream>>>(out_acc, rowsum, bvec, out);
}

// Round 4
// 331.193 us; speedup vs baseline: 1.1478x; 1.1478x over previous
//
#include <hip/hip_runtime.h>
#include <stdint.h>

#define NPTS 8192
#define DIM  512
#define ODIM 512

typedef __attribute__((ext_vector_type(8))) short short8;
typedef __attribute__((ext_vector_type(4))) float f32x4;

__device__ __forceinline__ void gload_lds16(const void* g, void* l) {
  __builtin_amdgcn_global_load_lds(
      (__attribute__((address_space(1))) void*)g,
      (__attribute__((address_space(3))) void*)l, 16, 0, 0);
}

// round-to-nearest-even f32 -> bf16 bits (values are finite here)
__device__ __forceinline__ short f2bf(float f) {
  uint32_t u = __float_as_uint(f);
  u = (u + 0x7FFFu + ((u >> 16) & 1u)) >> 16;
  return (short)u;
}

// counted-vmcnt barrier (T4): N loads may stay in flight across the barrier.
#define VMB(N) do {                                          \
    asm volatile("s_waitcnt vmcnt(" #N ")" ::: "memory");    \
    __builtin_amdgcn_sched_barrier(0);                       \
    __builtin_amdgcn_s_barrier();                            \
    __builtin_amdgcn_sched_barrier(0);                       \
  } while (0)

// ---------------------------------------------------------------------------
// 256x256 NT GEMM core, 8-phase schedule (T2+T3+T4+T5).
// BK=64, 2 LDS buffers (2 x 64 KiB = 128 KiB), 8 waves (2M x 4N),
// per-wave C = 128x64. 4 phases per K-tile:
//   p0: ds_read afA(8)+bb0(4) | stage SA0(t+1) | vmcnt(4)+bar | 16 MFMA Qa
//   p1: ds_read bb1(4)        | stage SB0(t+1) | vmcnt(4)+bar | 16 MFMA Qb
//   p2: ds_read afB(8)        | stage SB1(t+1) | vmcnt(4)+bar | 16 MFMA Qc
//   p3: (regs held)           | stage SA1(t+1) | vmcnt(4)+bar | 16 MFMA Qd
// Issue->use lag of every staged half >= 3 phases; vmcnt(4) allows exactly the
// newest 2 halves in flight => all reads covered, loads never drain to 0.
// Race-freedom: stages write buffer t+1 (!= read buffer t); at tile boundary
// a fast wave's stage into buffer t targets region SA0/SB0 while the slowest
// wave (1-barrier skew) is in p3 MFMA, which touches no LDS.
// LDS rows permuted so each staged half is contiguous:
//   A: phys = mh*128 + wr*64 + rr (logical row = wr*128 + mh*64 + rr)
//   B: phys = nh*128 + wc*32  + rr (logical row = wc*64  + nh*32 + rr)
// Swizzle (T2): 16B chunk slot = c ^ (phys_row & 7), applied on the global
// source (linear LDS dest, rule 21) and on ds_read (phys&7 == fr&7) -> each
// 8-lane cycle group covers all 32 banks: conflict-free ds_read_b128.
// ---------------------------------------------------------------------------
__device__ __forceinline__ void gemm256_8ph(const short* __restrict__ A,
                                            const short* __restrict__ B,
                                            int K, int lda, int ldb,
                                            short* lds, f32x4 acc[8][4]) {
  const int tid = threadIdx.x, wid = tid >> 6, lane = tid & 63;
  const int wr = wid >> 2, wc = wid & 3, fr = lane & 15, fg = (lane >> 4) & 3;
  const int nt = K >> 6;
  const int rp = tid >> 3, slot = tid & 7;
  const int ch = slot ^ (rp & 7);               // pre-swizzled source chunk

  // staging sources: sweep u covers phys rows u*64 .. u*64+63 of its matrix
  const short* srcA[4]; const short* srcB[4];
#pragma unroll
  for (int u = 0; u < 4; ++u) {
    // A: phys u*64+rp -> logical (u&1)*128 + (u>>1)*64 + rp
    srcA[u] = A + (size_t)((u & 1) * 128 + (u >> 1) * 64 + rp) * lda + ch * 8;
    // B: phys u*64+rp -> logical wc'*64 + nh*32 + rr
    srcB[u] = B + (size_t)(((u * 2 + (rp >> 5)) & 3) * 64 + (u >> 1) * 32 + (rp & 31)) * ldb + ch * 8;
  }

  // ds_read swizzled chunk offsets (shorts): c(kk) = ((kk*4+fg)^(fr&7))*8
  const int c0 = ((0 * 4 + fg) ^ (fr & 7)) * 8;
  const int c1 = ((1 * 4 + fg) ^ (fr & 7)) * 8;
  // per-thread row bases (shorts, x64 per row)
  const int aRow = wr * 64 + fr;                // + mh*128 + m*16
  const int bRow = wc * 32 + fr;                // + nh*128 + n*16

  // prologue: stage tile 0 in steady-state order SA0,SB0,SB1,SA1
#pragma unroll
  for (int s = 0; s < 2; ++s) gload_lds16(srcA[s], lds + s * 4096 + wid * 512);
#pragma unroll
  for (int s = 0; s < 2; ++s) gload_lds16(srcB[s], lds + 16384 + s * 4096 + wid * 512);
#pragma unroll
  for (int s = 2; s < 4; ++s) gload_lds16(srcB[s], lds + 16384 + s * 4096 + wid * 512);
#pragma unroll
  for (int s = 2; s < 4; ++s) gload_lds16(srcA[s], lds + s * 4096 + wid * 512);
  VMB(4);   // SA0,SB0 landed (oldest); SB1,SA1 may be in flight

  for (int t = 0; t < nt; ++t) {
    const int buf  = (t & 1) << 15;             // shorts
    const int nbuf = buf ^ 32768;
    const bool pf  = (t + 1) < nt;
    const int k1   = (t + 1) << 6;
    const short* sA = lds + buf;
    const short* sB = lds + buf + 16384;
    short8 afA[4][2], afB[4][2], bb0[2][2], bb1[2][2];

    // ---- phase 0: read afA (mh=0) + bb0 (nh=0); stage SA0(t+1)
#pragma unroll
    for (int m = 0; m < 4; ++m) {
      const int r = aRow + m * 16;              // mh=0
      afA[m][0] = *(const short8*)(sA + r * 64 + c0);
      afA[m][1] = *(const short8*)(sA + r * 64 + c1);
    }
#pragma unroll
    for (int n = 0; n < 2; ++n) {
      const int r = bRow + n * 16;              // nh=0
      bb0[n][0] = *(const short8*)(sB + r * 64 + c0);
      bb0[n][1] = *(const short8*)(sB + r * 64 + c1);
    }
    if (pf) {
#pragma unroll
      for (int s = 0; s < 2; ++s) gload_lds16(srcA[s] + k1, lds + nbuf + s * 4096 + wid * 512);
    }
    VMB(4);
    __builtin_amdgcn_s_setprio(1);
#pragma unroll
    for (int kk = 0; kk < 2; ++kk)
#pragma unroll
      for (int m = 0; m < 4; ++m)
#pragma unroll
        for (int n = 0; n < 2; ++n)
          acc[m][n] = __builtin_amdgcn_mfma_f32_16x16x32_bf16(afA[m][kk], bb0[n][kk], acc[m][n], 0, 0, 0);
    __builtin_amdgcn_s_setprio(0);

    // ---- phase 1: read bb1 (nh=1); stage SB0(t+1)
#pragma unroll
    for (int n = 0; n < 2; ++n) {
      const int r = 128 + bRow + n * 16;        // nh=1
      bb1[n][0] = *(const short8*)(sB + r * 64 + c0);
      bb1[n][1] = *(const short8*)(sB + r * 64 + c1);
    }
    if (pf) {
#pragma unroll
      for (int s = 0; s < 2; ++s) gload_lds16(srcB[s] + k1, lds + nbuf + 16384 + s * 4096 + wid * 512);
    }
    VMB(4);
    __builtin_amdgcn_s_setprio(1);
#pragma unroll
    for (int kk = 0; kk < 2; ++kk)
#pragma unroll
      for (int m = 0; m < 4; ++m)
#pragma unroll
        for (int n = 0; n < 2; ++n)
          acc[m][2 + n] = __builtin_amdgcn_mfma_f32_16x16x32_bf16(afA[m][kk], bb1[n][kk], acc[m][2 + n], 0, 0, 0);
    __builtin_amdgcn_s_setprio(0);

    // ---- phase 2: read afB (mh=1); stage SB1(t+1)
#pragma unroll
    for (int m = 0; m < 4; ++m) {
      const int r = 128 + aRow + m * 16;        // mh=1
      afB[m][0] = *(const short8*)(sA + r * 64 + c0);
      afB[m][1] = *(const short8*)(sA + r * 64 + c1);
    }
    if (pf) {
#pragma unroll
      for (int s = 2; s < 4; ++s) gload_lds16(srcB[s] + k1, lds + nbuf + 16384 + s * 4096 + wid * 512);
    }
    VMB(4);
    __builtin_amdgcn_s_setprio(1);
#pragma unroll
    for (int kk = 0; kk < 2; ++kk)
#pragma unroll
      for (int m = 0; m < 4; ++m)
#pragma unroll
        for (int n = 0; n < 2; ++n)
          acc[4 + m][2 + n] = __builtin_amdgcn_mfma_f32_16x16x32_bf16(afB[m][kk], bb1[n][kk], acc[4 + m][2 + n], 0, 0, 0);
    __builtin_amdgcn_s_setprio(0);

    // ---- phase 3: (bb0 held in regs); stage SA1(t+1)
    if (pf) {
#pragma unroll
      for (int s = 2; s < 4; ++s) gload_lds16(srcA[s] + k1, lds + nbuf + s * 4096 + wid * 512);
    }
    VMB(4);
    __builtin_amdgcn_s_setprio(1);
#pragma unroll
    for (int kk = 0; kk < 2; ++kk)
#pragma unroll
      for (int m = 0; m < 4; ++m)
#pragma unroll
        for (int n = 0; n < 2; ++n)
          acc[4 + m][n] = __builtin_amdgcn_mfma_f32_16x16x32_bf16(afB[m][kk], bb0[n][kk], acc[4 + m][n], 0, 0, 0);
    __builtin_amdgcn_s_setprio(0);
  }
}

#define ZERO_ACC8(acc)                       \
  {                                          \
    f32x4 _z = {0.f, 0.f, 0.f, 0.f};         \
    _Pragma("unroll")                        \
    for (int m = 0; m < 8; ++m)              \
      _Pragma("unroll")                      \
      for (int n = 0; n < 4; ++n) acc[m][n] = _z; \
  }

// ---------------------------------------------------------------------------
// legacy 128x128 core (small YbT GEMM only)
// ---------------------------------------------------------------------------
__device__ __forceinline__ void gemm_core_nt(const short* __restrict__ A,
                                             const short* __restrict__ B,
                                             int K, int lda, int ldb,
                                             short* smem, f32x4 acc[4][4]) {
  const int tid  = threadIdx.x;
  const int wid  = tid >> 6;
  const int lane = tid & 63;
  const int wr = wid >> 1, wc = wid & 1;
  const int sr = lane >> 2;
  const int sc = (lane & 3) << 3;
  const int fr = lane & 15, fg = lane >> 4;
  short* sA = smem;
  short* sB = smem + 4096;
  short* dA0 = sA + wid * 512;
  short* dA1 = sA + 2048 + wid * 512;
  short* dB0 = sB + wid * 512;
  short* dB1 = sB + 2048 + wid * 512;
  const short* pa0 = A + (size_t)(wid * 16 + sr) * lda + sc;
  const short* pa1 = A + (size_t)(64 + wid * 16 + sr) * lda + sc;
  const short* pb0 = B + (size_t)(wid * 16 + sr) * ldb + sc;
  const short* pb1 = B + (size_t)(64 + wid * 16 + sr) * ldb + sc;

  for (int k0 = 0; k0 < K; k0 += 32) {
    gload_lds16(pa0 + k0, dA0);
    gload_lds16(pa1 + k0, dA1);
    gload_lds16(pb0 + k0, dB0);
    gload_lds16(pb1 + k0, dB1);
    __syncthreads();
    short8 af[4], bb[4];
#pragma unroll
    for (int m = 0; m < 4; ++m)
      af[m] = *(const short8*)(sA + (wr * 64 + m * 16 + fr) * 32 + fg * 8);
#pragma unroll
    for (int n = 0; n < 4; ++n)
      bb[n] = *(const short8*)(sB + (wc * 64 + n * 16 + fr) * 32 + fg * 8);
#pragma unroll
    for (int m = 0; m < 4; ++m)
#pragma unroll
      for (int n = 0; n < 4; ++n)
        acc[m][n] = __builtin_amdgcn_mfma_f32_16x16x32_bf16(af[m], bb[n], acc[m][n], 0, 0, 0);
    __syncthreads();
  }
}

#define ZERO_ACC4(acc)                       \
  {                                          \
    f32x4 _z = {0.f, 0.f, 0.f, 0.f};         \
    _Pragma("unroll")                        \
    for (int m = 0; m < 4; ++m)              \
      _Pragma("unroll")                      \
      for (int n = 0; n < 4; ++n) acc[m][n] = _z; \
  }

// K1: x (f32) -> xb (bf16), sq[i] = sum x[i]^2. One wave per row.
__global__ __launch_bounds__(256) void k_prep_x(const float* __restrict__ x,
                                                short* __restrict__ xb,
                                                float* __restrict__ sq) {
  const int row  = blockIdx.x * 4 + (threadIdx.x >> 6);
  const int lane = threadIdx.x & 63;
  const float* px = x + (size_t)row * DIM + lane * 8;
  const float4 v0 = *(const float4*)px;
  const float4 v1 = *(const float4*)(px + 4);
  float s = v0.x*v0.x + v0.y*v0.y + v0.z*v0.z + v0.w*v0.w +
            v1.x*v1.x + v1.y*v1.y + v1.z*v1.z + v1.w*v1.w;
  short8 o;
  o[0]=f2bf(v0.x); o[1]=f2bf(v0.y); o[2]=f2bf(v0.z); o[3]=f2bf(v0.w);
  o[4]=f2bf(v1.x); o[5]=f2bf(v1.y); o[6]=f2bf(v1.z); o[7]=f2bf(v1.w);
  *(short8*)(xb + (size_t)row * DIM + lane * 8) = o;
#pragma unroll
  for (int m = 32; m >= 1; m >>= 1) s += __shfl_xor(s, m);
  if (lane == 0) sq[row] = s;
}

// K1b: W (f32) -> Wb (bf16)
__global__ __launch_bounds__(256) void k_prep_w(const float* __restrict__ W,
                                                short* __restrict__ Wb) {
  const int idx = blockIdx.x * 256 + threadIdx.x;
  const float4 v0 = *(const float4*)(W + (size_t)idx * 8);
  const float4 v1 = *(const float4*)(W + (size_t)idx * 8 + 4);
  short8 o;
  o[0]=f2bf(v0.x); o[1]=f2bf(v0.y); o[2]=f2bf(v0.z); o[3]=f2bf(v0.w);
  o[4]=f2bf(v1.x); o[5]=f2bf(v1.y); o[6]=f2bf(v1.z); o[7]=f2bf(v1.w);
  *(short8*)(Wb + (size_t)idx * 8) = o;
}

// K2: YbT[o][i] = bf16( sum_d Wb[o][d] * xb[i][d] )  (Y = x@W.T, transposed)
__global__ __launch_bounds__(256) void k_ybt(const short* __restrict__ xb,
                                             const short* __restrict__ Wb,
                                             short* __restrict__ YbT) {
  __shared__ short smem[8192];
  f32x4 acc[4][4];
  ZERO_ACC4(acc);
  const int rowBase = blockIdx.y * 128;  // o
  const int colBase = blockIdx.x * 128;  // i
  gemm_core_nt(Wb + (size_t)rowBase * DIM, xb + (size_t)colBase * DIM,
               DIM, DIM, DIM, smem, acc);
  const int lane = threadIdx.x & 63, wid = threadIdx.x >> 6;
  const int wr = wid >> 1, wc = wid & 1, fr = lane & 15, fg = lane >> 4;
#pragma unroll
  for (int m = 0; m < 4; ++m)
#pragma unroll
    for (int n = 0; n < 4; ++n)
#pragma unroll
      for (int r = 0; r < 4; ++r) {
        const int ro = rowBase + wr * 64 + m * 16 + fg * 4 + r;
        const int ci = colBase + wc * 64 + n * 16 + fr;
        YbT[(size_t)ro * NPTS + ci] = f2bf(acc[m][n][r]);
      }
}

// K3 (8-phase 256^2): P[i][j] = bf16(exp(min(2*dot - si - sj,0)/2048)), rowsum +=
__global__ __launch_bounds__(512, 2) void k_pmat(const short* __restrict__ xb,
                                                 const float* __restrict__ sq,
                                                 short* __restrict__ P,
                                                 float* __restrict__ rowsum,
                                                 int jbase, int SW) {
  __shared__ short lds[65536];   // 128 KiB = 2 buffers x 64 KiB
  f32x4 acc[8][4];
  ZERO_ACC8(acc);
  const int rowBase = blockIdx.y * 256;      // i
  const int colTile = blockIdx.x * 256;      // j within strip
  const int jglob = jbase + colTile;
  gemm256_8ph(xb + (size_t)rowBase * DIM, xb + (size_t)jglob * DIM,
              DIM, DIM, DIM, lds, acc);
  const int lane = threadIdx.x & 63, wid = threadIdx.x >> 6;
  const int wr = wid >> 2, wc = wid & 3, fr = lane & 15, fg = lane >> 4;
  float sj[4];
#pragma unroll
  for (int n = 0; n < 4; ++n) sj[n] = sq[jglob + wc * 64 + n * 16 + fr];
#pragma unroll
  for (int m = 0; m < 8; ++m) {
#pragma unroll
    for (int r = 0; r < 4; ++r) {
      const int i = rowBase + wr * 128 + m * 16 + fg * 4 + r;
      const float si = sq[i];
      float rs = 0.f;
#pragma unroll
      for (int n = 0; n < 4; ++n) {
        const float t = fminf(2.f * acc[m][n][r] - si - sj[n], 0.f) * (1.0f / 2048.0f);
        const float w = __expf(t);
        rs += w;
        P[(size_t)i * SW + (colTile + wc * 64 + n * 16 + fr)] = f2bf(w);
      }
      rs += __shfl_xor(rs, 1);
      rs += __shfl_xor(rs, 2);
      rs += __shfl_xor(rs, 4);
      rs += __shfl_xor(rs, 8);
      if (fr == 0) atomicAdd(&rowsum[i], rs);
    }
  }
}

// K4 (8-phase 256^2): out_acc[i][o] += sum_j P[i][j] * YbT[o][j]  (z = K-split)
__global__ __launch_bounds__(512, 2) void k_pv(const short* __restrict__ P,
                                               const short* __restrict__ YbT,
                                               float* __restrict__ out_acc,
                                               int jbase, int SW, int klen) {
  __shared__ short lds[65536];   // 128 KiB = 2 buffers x 64 KiB
  f32x4 acc[8][4];
  ZERO_ACC8(acc);
  const int rowBase = blockIdx.y * 256;  // i
  const int colBase = blockIdx.x * 256;  // o
  const int kz = blockIdx.z * klen;
  gemm256_8ph(P + (size_t)rowBase * SW + kz,
              YbT + (size_t)colBase * NPTS + jbase + kz,
              klen, SW, NPTS, lds, acc);
  const int lane = threadIdx.x & 63, wid = threadIdx.x >> 6;
  const int wr = wid >> 2, wc = wid & 3, fr = lane & 15, fg = lane >> 4;
#pragma unroll
  for (int m = 0; m < 8; ++m)
#pragma unroll
    for (int n = 0; n < 4; ++n)
#pragma unroll
      for (int r = 0; r < 4; ++r) {
        const int i = rowBase + wr * 128 + m * 16 + fg * 4 + r;
        const int o = colBase + wc * 64 + n * 16 + fr;
        atomicAdd(&out_acc[(size_t)i * ODIM + o], acc[m][n][r]);
      }
}

// K5: out = out_acc / (rowsum + eps) + b
__global__ __launch_bounds__(256) void k_final(const float* __restrict__ out_acc,
                                               const float* __restrict__ rowsum,
                                               const float* __restrict__ bvec,
                                               float* __restrict__ out) {
  const int idx = blockIdx.x * 256 + threadIdx.x;
  const int i = idx >> 7;
  const int o = (idx & 127) << 2;
  const float inv = 1.f / (rowsum[i] + 1e-8f);
  const float4 a = *(const float4*)(out_acc + (size_t)i * ODIM + o);
  const float4 bb = *(const float4*)(bvec + o);
  float4 r;
  r.x = a.x * inv + bb.x;
  r.y = a.y * inv + bb.y;
  r.z = a.z * inv + bb.z;
  r.w = a.w * inv + bb.w;
  *(float4*)(out + (size_t)i * ODIM + o) = r;
}

extern "C" void kernel_launch(void* const* d_in, const int* in_sizes, int n_in,
                              void* d_out, int out_size, void* d_ws, size_t ws_size,
                              hipStream_t stream) {
  (void)in_sizes; (void)n_in; (void)out_size;
  const float* x = (const float*)d_in[0];
  const float* W = (const float*)d_in[1];
  const float* bvec = (const float*)d_in[2];
  float* out = (float*)d_out;
  char* ws = (char*)d_ws;

  // workspace carving (bytes)
  short* xb      = (short*)(ws + 0);                  //  8 MiB
  short* Wb      = (short*)(ws + 8388608);            //  0.5 MiB
  short* YbT     = (short*)(ws + 8912896);            //  8 MiB
  float* sq      = (float*)(ws + 17301504);           //  32 KiB
  float* rowsum  = (float*)(ws + 17334272);           //  32 KiB
  float* out_acc = (float*)(ws + 17367040);           //  16 MiB
  short* P       = (short*)(ws + 34144256);           //  up to 128 MiB

  // adaptive P-strip width so everything fits in ws (multiples of 256)
  size_t pav = ws_size > 34144256 ? ws_size - 34144256 : 0;
  int SW = 8192;
  while (SW > 256 && (size_t)NPTS * SW * 2 > pav) SW >>= 1;
  const int nstrips = NPTS / SW;
  int ksplit = SW / 2048;
  if (ksplit < 1) ksplit = 1;
  if (ksplit > 4) ksplit = 4;
  const int klen = SW / ksplit;

  hipMemsetAsync(rowsum, 0, NPTS * sizeof(float), stream);
  hipMemsetAsync(out_acc, 0, (size_t)NPTS * ODIM * sizeof(float), stream);

  k_prep_x<<<dim3(NPTS / 4), 256, 0, stream>>>(x, xb, sq);
  k_prep_w<<<dim3(ODIM * DIM / 8 / 256), 256, 0, stream>>>(W, Wb);
  k_ybt<<<dim3(NPTS / 128, ODIM / 128), 256, 0, stream>>>(xb, Wb, YbT);

  for (int s = 0; s < nstrips; ++s) {
    const int jbase = s * SW;
    k_pmat<<<dim3(SW / 256, NPTS / 256), 512, 0, stream>>>(xb, sq, P, rowsum, jbase, SW);
    k_pv<<<dim3(ODIM / 256, NPTS / 256, ksplit), 512, 0, stream>>>(P, YbT, out_acc, jbase, SW, klen);
  }

  k_final<<<dim3(NPTS * ODIM / 4 / 256), 256, 0, stream>>>(out_acc, rowsum, bvec, out);
}

// Round 5
// 330.379 us; speedup vs baseline: 1.1506x; 1.0025x over previous
//
#include <hip/hip_runtime.h>
#include <stdint.h>

#define NPTS 8192
#define DIM  512
#define ODIM 512

typedef __attribute__((ext_vector_type(8))) short short8;
typedef __attribute__((ext_vector_type(4))) float f32x4;

__device__ __forceinline__ void gload_lds16(const void* g, void* l) {
  __builtin_amdgcn_global_load_lds(
      (__attribute__((address_space(1))) void*)g,
      (__attribute__((address_space(3))) void*)l, 16, 0, 0);
}

// round-to-nearest-even f32 -> bf16 bits (values are finite here)
__device__ __forceinline__ short f2bf(float f) {
  uint32_t u = __float_as_uint(f);
  u = (u + 0x7FFFu + ((u >> 16) & 1u)) >> 16;
  return (short)u;
}

// counted-vmcnt barrier (T4): wait until <=N of OUR loads outstanding, then
// block barrier. Placed BEFORE the reads that consume the landed data.
#define VMB(N) do {                                          \
    asm volatile("s_waitcnt vmcnt(" #N ")" ::: "memory");    \
    __builtin_amdgcn_sched_barrier(0);                       \
    __builtin_amdgcn_s_barrier();                            \
    __builtin_amdgcn_sched_barrier(0);                       \
  } while (0)

#define BARRIER_ONLY() do {                                  \
    asm volatile("" ::: "memory");                           \
    __builtin_amdgcn_sched_barrier(0);                       \
    __builtin_amdgcn_s_barrier();                            \
    __builtin_amdgcn_sched_barrier(0);                       \
  } while (0)

// ---------------------------------------------------------------------------
// 256x256 NT GEMM core, 4-region schedule with template-style counted waits.
// BK=64, 2 LDS buffers (2 x 64 KiB = 128 KiB), 8 waves (2M x 4N),
// per-wave C = 128x64. Per K-tile t (steady state):
//   p0: VMB(4) | ds_read afA(8)+bb0(4) | stage A0,B0(t+1) (4 ld) | 16 MFMA Qa
//   p1: VMB(4) | ds_read bb1(4)        | stage B1,A1(t+1) (4 ld) | 16 MFMA Qb
//   p2: barrier | ds_read afB(8)       |                         | 16 MFMA Qc
//   p3: barrier | (regs held)          |                         | 16 MFMA Qd
// FIFO trace (per-wave, 2 loads per stage-half):
//   entering p0: outstanding = tile t's 8 loads (issued t-1 p0/p1).
//   p0 VMB(4) lands A0(t),B0(t)  — issued 4 phases ago; read this phase.
//   p1 VMB(4) lands B1(t),A1(t)  — issued 4 phases ago; B1 read now, A1 at p2.
//   p2/p3 need no vmem wait (A1 already forced at p1).
// Tail tile (no prefetch): waits 4 / 2 / 0 at p0/p1/p2.
// Cross-wave visibility: each wave's own vmcnt forces ITS loads, then the
// same-VMB barrier orders all waves' forcings before any read.
// Anti-dependency: stage at t pX overwrites buf(t-1) regions last READ at
// tile t-1 (>=4 barriers earlier) — safe.
// LDS layout + T2 swizzle identical to round-4 (verified: 0 bank conflicts):
// chunk slot = c ^ (phys_row & 7), pre-swizzled global source (linear LDS
// dest), same involution on ds_read.
// ---------------------------------------------------------------------------
__device__ __forceinline__ void gemm256_8ph(const short* __restrict__ A,
                                            const short* __restrict__ B,
                                            int K, int lda, int ldb,
                                            short* lds, f32x4 acc[8][4]) {
  const int tid = threadIdx.x, wid = tid >> 6, lane = tid & 63;
  const int wr = wid >> 2, wc = wid & 3, fr = lane & 15, fg = (lane >> 4) & 3;
  const int nt = K >> 6;
  const int rp = tid >> 3, slot = tid & 7;
  const int ch = slot ^ (rp & 7);               // pre-swizzled source chunk

  // staging sources: sweep u covers phys rows u*64 .. u*64+63 of its matrix
  const short* srcA[4]; const short* srcB[4];
#pragma unroll
  for (int u = 0; u < 4; ++u) {
    // A: phys u*64+rp -> logical (u&1)*128 + (u>>1)*64 + rp
    srcA[u] = A + (size_t)((u & 1) * 128 + (u >> 1) * 64 + rp) * lda + ch * 8;
    // B: phys u*64+rp -> logical row per round-4 mapping (verified)
    srcB[u] = B + (size_t)(((u * 2 + (rp >> 5)) & 3) * 64 + (u >> 1) * 32 + (rp & 31)) * ldb + ch * 8;
  }

  // ds_read swizzled chunk offsets (shorts): c(kk) = ((kk*4+fg)^(fr&7))*8
  const int c0 = (fg ^ (fr & 7)) * 8;
  const int c1 = ((4 + fg) ^ (fr & 7)) * 8;
  const int aRow = wr * 64 + fr;                // + mh*128 + m*16
  const int bRow = wc * 32 + fr;                // + nh*128 + n*16

  // prologue: stage tile 0, FIFO order A0,B0,B1,A1 (8 loads, no wait here)
#pragma unroll
  for (int s = 0; s < 2; ++s) gload_lds16(srcA[s], lds + s * 4096 + wid * 512);
#pragma unroll
  for (int s = 0; s < 2; ++s) gload_lds16(srcB[s], lds + 16384 + s * 4096 + wid * 512);
#pragma unroll
  for (int s = 2; s < 4; ++s) gload_lds16(srcB[s], lds + 16384 + s * 4096 + wid * 512);
#pragma unroll
  for (int s = 2; s < 4; ++s) gload_lds16(srcA[s], lds + s * 4096 + wid * 512);

  for (int t = 0; t < nt; ++t) {
    const int buf  = (t & 1) << 15;             // shorts
    const int nbuf = buf ^ 32768;
    const bool last = (t + 1) >= nt;
    const int k1   = (t + 1) << 6;
    const short* sA = lds + buf;
    const short* sB = lds + buf + 16384;
    short8 afA[4][2], afB[4][2], bb0[2][2], bb1[2][2];

    // ---- phase 0: wait A0,B0(t) | read afA+bb0 | stage A0,B0(t+1) | Qa
    VMB(4);
#pragma unroll
    for (int m = 0; m < 4; ++m) {
      const int r = aRow + m * 16;              // mh=0
      afA[m][0] = *(const short8*)(sA + r * 64 + c0);
      afA[m][1] = *(const short8*)(sA + r * 64 + c1);
    }
#pragma unroll
    for (int n = 0; n < 2; ++n) {
      const int r = bRow + n * 16;              // nh=0
      bb0[n][0] = *(const short8*)(sB + r * 64 + c0);
      bb0[n][1] = *(const short8*)(sB + r * 64 + c1);
    }
    if (!last) {
#pragma unroll
      for (int s = 0; s < 2; ++s) gload_lds16(srcA[s] + k1, lds + nbuf + s * 4096 + wid * 512);
#pragma unroll
      for (int s = 0; s < 2; ++s) gload_lds16(srcB[s] + k1, lds + nbuf + 16384 + s * 4096 + wid * 512);
    }
    __builtin_amdgcn_s_setprio(1);
#pragma unroll
    for (int kk = 0; kk < 2; ++kk)
#pragma unroll
      for (int m = 0; m < 4; ++m)
#pragma unroll
        for (int n = 0; n < 2; ++n)
          acc[m][n] = __builtin_amdgcn_mfma_f32_16x16x32_bf16(afA[m][kk], bb0[n][kk], acc[m][n], 0, 0, 0);
    __builtin_amdgcn_s_setprio(0);

    // ---- phase 1: wait B1,A1(t) | read bb1 | stage B1,A1(t+1) | Qb
    if (!last) { VMB(4); } else { VMB(2); }
#pragma unroll
    for (int n = 0; n < 2; ++n) {
      const int r = 128 + bRow + n * 16;        // nh=1
      bb1[n][0] = *(const short8*)(sB + r * 64 + c0);
      bb1[n][1] = *(const short8*)(sB + r * 64 + c1);
    }
    if (!last) {
#pragma unroll
      for (int s = 2; s < 4; ++s) gload_lds16(srcB[s] + k1, lds + nbuf + 16384 + s * 4096 + wid * 512);
#pragma unroll
      for (int s = 2; s < 4; ++s) gload_lds16(srcA[s] + k1, lds + nbuf + s * 4096 + wid * 512);
    }
    __builtin_amdgcn_s_setprio(1);
#pragma unroll
    for (int kk = 0; kk < 2; ++kk)
#pragma unroll
      for (int m = 0; m < 4; ++m)
#pragma unroll
        for (int n = 0; n < 2; ++n)
          acc[m][2 + n] = __builtin_amdgcn_mfma_f32_16x16x32_bf16(afA[m][kk], bb1[n][kk], acc[m][2 + n], 0, 0, 0);
    __builtin_amdgcn_s_setprio(0);

    // ---- phase 2: read afB (A1 landed at p1's wait) | Qc
    if (!last) { BARRIER_ONLY(); } else { VMB(0); }
#pragma unroll
    for (int m = 0; m < 4; ++m) {
      const int r = 128 + aRow + m * 16;        // mh=1
      afB[m][0] = *(const short8*)(sA + r * 64 + c0);
      afB[m][1] = *(const short8*)(sA + r * 64 + c1);
    }
    __builtin_amdgcn_s_setprio(1);
#pragma unroll
    for (int kk = 0; kk < 2; ++kk)
#pragma unroll
      for (int m = 0; m < 4; ++m)
#pragma unroll
        for (int n = 0; n < 2; ++n)
          acc[4 + m][2 + n] = __builtin_amdgcn_mfma_f32_16x16x32_bf16(afB[m][kk], bb1[n][kk], acc[4 + m][2 + n], 0, 0, 0);
    __builtin_amdgcn_s_setprio(0);

    // ---- phase 3: pure-MFMA region (regs held) | Qd
    BARRIER_ONLY();
    __builtin_amdgcn_s_setprio(1);
#pragma unroll
    for (int kk = 0; kk < 2; ++kk)
#pragma unroll
      for (int m = 0; m < 4; ++m)
#pragma unroll
        for (int n = 0; n < 2; ++n)
          acc[4 + m][n] = __builtin_amdgcn_mfma_f32_16x16x32_bf16(afB[m][kk], bb0[n][kk], acc[4 + m][n], 0, 0, 0);
    __builtin_amdgcn_s_setprio(0);
  }
}

#define ZERO_ACC8(acc)                       \
  {                                          \
    f32x4 _z = {0.f, 0.f, 0.f, 0.f};         \
    _Pragma("unroll")                        \
    for (int m = 0; m < 8; ++m)              \
      _Pragma("unroll")                      \
      for (int n = 0; n < 4; ++n) acc[m][n] = _z; \
  }

// ---------------------------------------------------------------------------
// legacy 128x128 core (small YbT GEMM only)
// ---------------------------------------------------------------------------
__device__ __forceinline__ void gemm_core_nt(const short* __restrict__ A,
                                             const short* __restrict__ B,
                                             int K, int lda, int ldb,
                                             short* smem, f32x4 acc[4][4]) {
  const int tid  = threadIdx.x;
  const int wid  = tid >> 6;
  const int lane = tid & 63;
  const int wr = wid >> 1, wc = wid & 1;
  const int sr = lane >> 2;
  const int sc = (lane & 3) << 3;
  const int fr = lane & 15, fg = lane >> 4;
  short* sA = smem;
  short* sB = smem + 4096;
  short* dA0 = sA + wid * 512;
  short* dA1 = sA + 2048 + wid * 512;
  short* dB0 = sB + wid * 512;
  short* dB1 = sB + 2048 + wid * 512;
  const short* pa0 = A + (size_t)(wid * 16 + sr) * lda + sc;
  const short* pa1 = A + (size_t)(64 + wid * 16 + sr) * lda + sc;
  const short* pb0 = B + (size_t)(wid * 16 + sr) * ldb + sc;
  const short* pb1 = B + (size_t)(64 + wid * 16 + sr) * ldb + sc;

  for (int k0 = 0; k0 < K; k0 += 32) {
    gload_lds16(pa0 + k0, dA0);
    gload_lds16(pa1 + k0, dA1);
    gload_lds16(pb0 + k0, dB0);
    gload_lds16(pb1 + k0, dB1);
    __syncthreads();
    short8 af[4], bb[4];
#pragma unroll
    for (int m = 0; m < 4; ++m)
      af[m] = *(const short8*)(sA + (wr * 64 + m * 16 + fr) * 32 + fg * 8);
#pragma unroll
    for (int n = 0; n < 4; ++n)
      bb[n] = *(const short8*)(sB + (wc * 64 + n * 16 + fr) * 32 + fg * 8);
#pragma unroll
    for (int m = 0; m < 4; ++m)
#pragma unroll
      for (int n = 0; n < 4; ++n)
        acc[m][n] = __builtin_amdgcn_mfma_f32_16x16x32_bf16(af[m], bb[n], acc[m][n], 0, 0, 0);
    __syncthreads();
  }
}

#define ZERO_ACC4(acc)                       \
  {                                          \
    f32x4 _z = {0.f, 0.f, 0.f, 0.f};         \
    _Pragma("unroll")                        \
    for (int m = 0; m < 4; ++m)              \
      _Pragma("unroll")                      \
      for (int n = 0; n < 4; ++n) acc[m][n] = _z; \
  }

// K1: x (f32) -> xb (bf16), sq[i] = sum x[i]^2. One wave per row.
__global__ __launch_bounds__(256) void k_prep_x(const float* __restrict__ x,
                                                short* __restrict__ xb,
                                                float* __restrict__ sq) {
  const int row  = blockIdx.x * 4 + (threadIdx.x >> 6);
  const int lane = threadIdx.x & 63;
  const float* px = x + (size_t)row * DIM + lane * 8;
  const float4 v0 = *(const float4*)px;
  const float4 v1 = *(const float4*)(px + 4);
  float s = v0.x*v0.x + v0.y*v0.y + v0.z*v0.z + v0.w*v0.w +
            v1.x*v1.x + v1.y*v1.y + v1.z*v1.z + v1.w*v1.w;
  short8 o;
  o[0]=f2bf(v0.x); o[1]=f2bf(v0.y); o[2]=f2bf(v0.z); o[3]=f2bf(v0.w);
  o[4]=f2bf(v1.x); o[5]=f2bf(v1.y); o[6]=f2bf(v1.z); o[7]=f2bf(v1.w);
  *(short8*)(xb + (size_t)row * DIM + lane * 8) = o;
#pragma unroll
  for (int m = 32; m >= 1; m >>= 1) s += __shfl_xor(s, m);
  if (lane == 0) sq[row] = s;
}

// K1b: W (f32) -> Wb (bf16)
__global__ __launch_bounds__(256) void k_prep_w(const float* __restrict__ W,
                                                short* __restrict__ Wb) {
  const int idx = blockIdx.x * 256 + threadIdx.x;
  const float4 v0 = *(const float4*)(W + (size_t)idx * 8);
  const float4 v1 = *(const float4*)(W + (size_t)idx * 8 + 4);
  short8 o;
  o[0]=f2bf(v0.x); o[1]=f2bf(v0.y); o[2]=f2bf(v0.z); o[3]=f2bf(v0.w);
  o[4]=f2bf(v1.x); o[5]=f2bf(v1.y); o[6]=f2bf(v1.z); o[7]=f2bf(v1.w);
  *(short8*)(Wb + (size_t)idx * 8) = o;
}

// K2: YbT[o][i] = bf16( sum_d Wb[o][d] * xb[i][d] )  (Y = x@W.T, transposed)
__global__ __launch_bounds__(256) void k_ybt(const short* __restrict__ xb,
                                             const short* __restrict__ Wb,
                                             short* __restrict__ YbT) {
  __shared__ short smem[8192];
  f32x4 acc[4][4];
  ZERO_ACC4(acc);
  const int rowBase = blockIdx.y * 128;  // o
  const int colBase = blockIdx.x * 128;  // i
  gemm_core_nt(Wb + (size_t)rowBase * DIM, xb + (size_t)colBase * DIM,
               DIM, DIM, DIM, smem, acc);
  const int lane = threadIdx.x & 63, wid = threadIdx.x >> 6;
  const int wr = wid >> 1, wc = wid & 1, fr = lane & 15, fg = lane >> 4;
#pragma unroll
  for (int m = 0; m < 4; ++m)
#pragma unroll
    for (int n = 0; n < 4; ++n)
#pragma unroll
      for (int r = 0; r < 4; ++r) {
        const int ro = rowBase + wr * 64 + m * 16 + fg * 4 + r;
        const int ci = colBase + wc * 64 + n * 16 + fr;
        YbT[(size_t)ro * NPTS + ci] = f2bf(acc[m][n][r]);
      }
}

// K3 (counted-wait 256^2): P[i][j] = bf16(exp(min(2*dot - si - sj,0)/2048)), rowsum +=
__global__ __launch_bounds__(512, 2) void k_pmat(const short* __restrict__ xb,
                                                 const float* __restrict__ sq,
                                                 short* __restrict__ P,
                                                 float* __restrict__ rowsum,
                                                 int jbase, int SW) {
  __shared__ short lds[65536];   // 128 KiB = 2 buffers x 64 KiB
  f32x4 acc[8][4];
  ZERO_ACC8(acc);
  const int rowBase = blockIdx.y * 256;      // i
  const int colTile = blockIdx.x * 256;      // j within strip
  const int jglob = jbase + colTile;
  gemm256_8ph(xb + (size_t)rowBase * DIM, xb + (size_t)jglob * DIM,
              DIM, DIM, DIM, lds, acc);
  const int lane = threadIdx.x & 63, wid = threadIdx.x >> 6;
  const int wr = wid >> 2, wc = wid & 3, fr = lane & 15, fg = lane >> 4;
  float sj[4];
#pragma unroll
  for (int n = 0; n < 4; ++n) sj[n] = sq[jglob + wc * 64 + n * 16 + fr];
#pragma unroll
  for (int m = 0; m < 8; ++m) {
#pragma unroll
    for (int r = 0; r < 4; ++r) {
      const int i = rowBase + wr * 128 + m * 16 + fg * 4 + r;
      const float si = sq[i];
      float rs = 0.f;
#pragma unroll
      for (int n = 0; n < 4; ++n) {
        const float t = fminf(2.f * acc[m][n][r] - si - sj[n], 0.f) * (1.0f / 2048.0f);
        const float w = __expf(t);
        rs += w;
        P[(size_t)i * SW + (colTile + wc * 64 + n * 16 + fr)] = f2bf(w);
      }
      rs += __shfl_xor(rs, 1);
      rs += __shfl_xor(rs, 2);
      rs += __shfl_xor(rs, 4);
      rs += __shfl_xor(rs, 8);
      if (fr == 0) atomicAdd(&rowsum[i], rs);
    }
  }
}

// K4 (counted-wait 256^2): out_acc[i][o] += sum_j P[i][j] * YbT[o][j]  (z = K-split)
__global__ __launch_bounds__(512, 2) void k_pv(const short* __restrict__ P,
                                               const short* __restrict__ YbT,
                                               float* __restrict__ out_acc,
                                               int jbase, int SW, int klen) {
  __shared__ short lds[65536];   // 128 KiB = 2 buffers x 64 KiB
  f32x4 acc[8][4];
  ZERO_ACC8(acc);
  const int rowBase = blockIdx.y * 256;  // i
  const int colBase = blockIdx.x * 256;  // o
  const int kz = blockIdx.z * klen;
  gemm256_8ph(P + (size_t)rowBase * SW + kz,
              YbT + (size_t)colBase * NPTS + jbase + kz,
              klen, SW, NPTS, lds, acc);
  const int lane = threadIdx.x & 63, wid = threadIdx.x >> 6;
  const int wr = wid >> 2, wc = wid & 3, fr = lane & 15, fg = lane >> 4;
#pragma unroll
  for (int m = 0; m < 8; ++m)
#pragma unroll
    for (int n = 0; n < 4; ++n)
#pragma unroll
      for (int r = 0; r < 4; ++r) {
        const int i = rowBase + wr * 128 + m * 16 + fg * 4 + r;
        const int o = colBase + wc * 64 + n * 16 + fr;
        atomicAdd(&out_acc[(size_t)i * ODIM + o], acc[m][n][r]);
      }
}

// K5: out = out_acc / (rowsum + eps) + b
__global__ __launch_bounds__(256) void k_final(const float* __restrict__ out_acc,
                                               const float* __restrict__ rowsum,
                                               const float* __restrict__ bvec,
                                               float* __restrict__ out) {
  const int idx = blockIdx.x * 256 + threadIdx.x;
  const int i = idx >> 7;
  const int o = (idx & 127) << 2;
  const float inv = 1.f / (rowsum[i] + 1e-8f);
  const float4 a = *(const float4*)(out_acc + (size_t)i * ODIM + o);
  const float4 bb = *(const float4*)(bvec + o);
  float4 r;
  r.x = a.x * inv + bb.x;
  r.y = a.y * inv + bb.y;
  r.z = a.z * inv + bb.z;
  r.w = a.w * inv + bb.w;
  *(float4*)(out + (size_t)i * ODIM + o) = r;
}

extern "C" void kernel_launch(void* const* d_in, const int* in_sizes, int n_in,
                              void* d_out, int out_size, void* d_ws, size_t ws_size,
                              hipStream_t stream) {
  (void)in_sizes; (void)n_in; (void)out_size;
  const float* x = (const float*)d_in[0];
  const float* W = (const float*)d_in[1];
  const float* bvec = (const float*)d_in[2];
  float* out = (float*)d_out;
  char* ws = (char*)d_ws;

  // workspace carving (bytes)
  short* xb      = (short*)(ws + 0);                  //  8 MiB
  short* Wb      = (short*)(ws + 8388608);            //  0.5 MiB
  short* YbT     = (short*)(ws + 8912896);            //  8 MiB
  float* sq      = (float*)(ws + 17301504);           //  32 KiB
  float* rowsum  = (float*)(ws + 17334272);           //  32 KiB
  float* out_acc = (float*)(ws + 17367040);           //  16 MiB
  short* P       = (short*)(ws + 34144256);           //  up to 128 MiB

  // adaptive P-strip width so everything fits in ws (multiples of 256)
  size_t pav = ws_size > 34144256 ? ws_size - 34144256 : 0;
  int SW = 8192;
  while (SW > 256 && (size_t)NPTS * SW * 2 > pav) SW >>= 1;
  const int nstrips = NPTS / SW;
  int ksplit = SW / 2048;
  if (ksplit < 1) ksplit = 1;
  if (ksplit > 4) ksplit = 4;
  const int klen = SW / ksplit;

  hipMemsetAsync(rowsum, 0, NPTS * sizeof(float), stream);
  hipMemsetAsync(out_acc, 0, (size_t)NPTS * ODIM * sizeof(float), stream);

  k_prep_x<<<dim3(NPTS / 4), 256, 0, stream>>>(x, xb, sq);
  k_prep_w<<<dim3(ODIM * DIM / 8 / 256), 256, 0, stream>>>(W, Wb);
  k_ybt<<<dim3(NPTS / 128, ODIM / 128), 256, 0, stream>>>(xb, Wb, YbT);

  for (int s = 0; s < nstrips; ++s) {
    const int jbase = s * SW;
    k_pmat<<<dim3(SW / 256, NPTS / 256), 512, 0, stream>>>(xb, sq, P, rowsum, jbase, SW);
    k_pv<<<dim3(ODIM / 256, NPTS / 256, ksplit), 512, 0, stream>>>(P, YbT, out_acc, jbase, SW, klen);
  }

  k_final<<<dim3(NPTS * ODIM / 4 / 256), 256, 0, stream>>>(out_acc, rowsum, bvec, out);
}

// Round 7
// 326.982 us; speedup vs baseline: 1.1626x; 1.0104x over previous
//
#include <hip/hip_runtime.h>
#include <stdint.h>

#define NPTS 8192
#define DIM  512
#define ODIM 512

typedef __attribute__((ext_vector_type(8))) short short8;
typedef __attribute__((ext_vector_type(4))) float f32x4;

__device__ __forceinline__ void gload_lds16(const void* g, void* l) {
  __builtin_amdgcn_global_load_lds(
      (__attribute__((address_space(1))) void*)g,
      (__attribute__((address_space(3))) void*)l, 16, 0, 0);
}

// round-to-nearest-even f32 -> bf16 bits (values are finite here)
__device__ __forceinline__ short f2bf(float f) {
  uint32_t u = __float_as_uint(f);
  u = (u + 0x7FFFu + ((u >> 16) & 1u)) >> 16;
  return (short)u;
}

// counted-vmcnt barrier (T4)
#define VMB(N) do {                                          \
    asm volatile("s_waitcnt vmcnt(" #N ")" ::: "memory");    \
    __builtin_amdgcn_sched_barrier(0);                       \
    __builtin_amdgcn_s_barrier();                            \
    __builtin_amdgcn_sched_barrier(0);                       \
  } while (0)

// ---------------------------------------------------------------------------
// 256x256 NT GEMM core — round-4 schedule (best measured: 154us, 0 bank confl).
// BK=64, 2 LDS buffers (128 KiB), 8 waves (2M x 4N), per-wave C = 128x64.
//   p0: ds_read afA(8)+bb0(4) | stage SA0(t+1) | VMB(4) | 16 MFMA Qa
//   p1: ds_read bb1(4)        | stage SB0(t+1) | VMB(4) | 16 MFMA Qb
//   p2: ds_read afB(8)        | stage SB1(t+1) | VMB(4) | 16 MFMA Qc
//   p3: (regs held)           | stage SA1(t+1) | VMB(4) | 16 MFMA Qd
// T2 swizzle: 16B chunk slot = c ^ (phys_row & 7), pre-swizzled global source
// (linear LDS dest, rule 21), same involution on ds_read — verified 0 confl.
// ---------------------------------------------------------------------------
__device__ __forceinline__ void gemm256_8ph(const short* __restrict__ A,
                                            const short* __restrict__ B,
                                            int K, int lda, int ldb,
                                            short* lds, f32x4 acc[8][4]) {
  const int tid = threadIdx.x, wid = tid >> 6, lane = tid & 63;
  const int wr = wid >> 2, wc = wid & 3, fr = lane & 15, fg = (lane >> 4) & 3;
  const int nt = K >> 6;
  const int rp = tid >> 3, slot = tid & 7;
  const int ch = slot ^ (rp & 7);               // pre-swizzled source chunk

  const short* srcA[4]; const short* srcB[4];
#pragma unroll
  for (int u = 0; u < 4; ++u) {
    srcA[u] = A + (size_t)((u & 1) * 128 + (u >> 1) * 64 + rp) * lda + ch * 8;
    srcB[u] = B + (size_t)(((u * 2 + (rp >> 5)) & 3) * 64 + (u >> 1) * 32 + (rp & 31)) * ldb + ch * 8;
  }

  const int c0 = (fg ^ (fr & 7)) * 8;
  const int c1 = ((4 + fg) ^ (fr & 7)) * 8;
  const int aRow = wr * 64 + fr;                // + mh*128 + m*16
  const int bRow = wc * 32 + fr;                // + nh*128 + n*16

  // prologue: stage tile 0 in steady-state order SA0,SB0,SB1,SA1
#pragma unroll
  for (int s = 0; s < 2; ++s) gload_lds16(srcA[s], lds + s * 4096 + wid * 512);
#pragma unroll
  for (int s = 0; s < 2; ++s) gload_lds16(srcB[s], lds + 16384 + s * 4096 + wid * 512);
#pragma unroll
  for (int s = 2; s < 4; ++s) gload_lds16(srcB[s], lds + 16384 + s * 4096 + wid * 512);
#pragma unroll
  for (int s = 2; s < 4; ++s) gload_lds16(srcA[s], lds + s * 4096 + wid * 512);
  VMB(4);   // SA0,SB0 landed; SB1,SA1 may be in flight

  for (int t = 0; t < nt; ++t) {
    const int buf  = (t & 1) << 15;             // shorts
    const int nbuf = buf ^ 32768;
    const bool pf  = (t + 1) < nt;
    const int k1   = (t + 1) << 6;
    const short* sA = lds + buf;
    const short* sB = lds + buf + 16384;
    short8 afA[4][2], afB[4][2], bb0[2][2], bb1[2][2];

    // ---- phase 0
#pragma unroll
    for (int m = 0; m < 4; ++m) {
      const int r = aRow + m * 16;
      afA[m][0] = *(const short8*)(sA + r * 64 + c0);
      afA[m][1] = *(const short8*)(sA + r * 64 + c1);
    }
#pragma unroll
    for (int n = 0; n < 2; ++n) {
      const int r = bRow + n * 16;
      bb0[n][0] = *(const short8*)(sB + r * 64 + c0);
      bb0[n][1] = *(const short8*)(sB + r * 64 + c1);
    }
    if (pf) {
#pragma unroll
      for (int s = 0; s < 2; ++s) gload_lds16(srcA[s] + k1, lds + nbuf + s * 4096 + wid * 512);
    }
    VMB(4);
    __builtin_amdgcn_s_setprio(1);
#pragma unroll
    for (int kk = 0; kk < 2; ++kk)
#pragma unroll
      for (int m = 0; m < 4; ++m)
#pragma unroll
        for (int n = 0; n < 2; ++n)
          acc[m][n] = __builtin_amdgcn_mfma_f32_16x16x32_bf16(afA[m][kk], bb0[n][kk], acc[m][n], 0, 0, 0);
    __builtin_amdgcn_s_setprio(0);

    // ---- phase 1
#pragma unroll
    for (int n = 0; n < 2; ++n) {
      const int r = 128 + bRow + n * 16;
      bb1[n][0] = *(const short8*)(sB + r * 64 + c0);
      bb1[n][1] = *(const short8*)(sB + r * 64 + c1);
    }
    if (pf) {
#pragma unroll
      for (int s = 0; s < 2; ++s) gload_lds16(srcB[s] + k1, lds + nbuf + 16384 + s * 4096 + wid * 512);
    }
    VMB(4);
    __builtin_amdgcn_s_setprio(1);
#pragma unroll
    for (int kk = 0; kk < 2; ++kk)
#pragma unroll
      for (int m = 0; m < 4; ++m)
#pragma unroll
        for (int n = 0; n < 2; ++n)
          acc[m][2 + n] = __builtin_amdgcn_mfma_f32_16x16x32_bf16(afA[m][kk], bb1[n][kk], acc[m][2 + n], 0, 0, 0);
    __builtin_amdgcn_s_setprio(0);

    // ---- phase 2
#pragma unroll
    for (int m = 0; m < 4; ++m) {
      const int r = 128 + aRow + m * 16;
      afB[m][0] = *(const short8*)(sA + r * 64 + c0);
      afB[m][1] = *(const short8*)(sA + r * 64 + c1);
    }
    if (pf) {
#pragma unroll
      for (int s = 2; s < 4; ++s) gload_lds16(srcB[s] + k1, lds + nbuf + 16384 + s * 4096 + wid * 512);
    }
    VMB(4);
    __builtin_amdgcn_s_setprio(1);
#pragma unroll
    for (int kk = 0; kk < 2; ++kk)
#pragma unroll
      for (int m = 0; m < 4; ++m)
#pragma unroll
        for (int n = 0; n < 2; ++n)
          acc[4 + m][2 + n] = __builtin_amdgcn_mfma_f32_16x16x32_bf16(afB[m][kk], bb1[n][kk], acc[4 + m][2 + n], 0, 0, 0);
    __builtin_amdgcn_s_setprio(0);

    // ---- phase 3
    if (pf) {
#pragma unroll
      for (int s = 2; s < 4; ++s) gload_lds16(srcA[s] + k1, lds + nbuf + s * 4096 + wid * 512);
    }
    VMB(4);
    __builtin_amdgcn_s_setprio(1);
#pragma unroll
    for (int kk = 0; kk < 2; ++kk)
#pragma unroll
      for (int m = 0; m < 4; ++m)
#pragma unroll
        for (int n = 0; n < 2; ++n)
          acc[4 + m][n] = __builtin_amdgcn_mfma_f32_16x16x32_bf16(afB[m][kk], bb0[n][kk], acc[4 + m][n], 0, 0, 0);
    __builtin_amdgcn_s_setprio(0);
  }
}

#define ZERO_ACC8(acc)                       \
  {                                          \
    f32x4 _z = {0.f, 0.f, 0.f, 0.f};         \
    _Pragma("unroll")                        \
    for (int m = 0; m < 8; ++m)              \
      _Pragma("unroll")                      \
      for (int n = 0; n < 4; ++n) acc[m][n] = _z; \
  }

// ---------------------------------------------------------------------------
// legacy 128x128 core (small YbT GEMM only)
// ---------------------------------------------------------------------------
__device__ __forceinline__ void gemm_core_nt(const short* __restrict__ A,
                                             const short* __restrict__ B,
                                             int K, int lda, int ldb,
                                             short* smem, f32x4 acc[4][4]) {
  const int tid  = threadIdx.x;
  const int wid  = tid >> 6;
  const int lane = tid & 63;
  const int wr = wid >> 1, wc = wid & 1;
  const int sr = lane >> 2;
  const int sc = (lane & 3) << 3;
  const int fr = lane & 15, fg = lane >> 4;
  short* sA = smem;
  short* sB = smem + 4096;
  short* dA0 = sA + wid * 512;
  short* dA1 = sA + 2048 + wid * 512;
  short* dB0 = sB + wid * 512;
  short* dB1 = sB + 2048 + wid * 512;
  const short* pa0 = A + (size_t)(wid * 16 + sr) * lda + sc;
  const short* pa1 = A + (size_t)(64 + wid * 16 + sr) * lda + sc;
  const short* pb0 = B + (size_t)(wid * 16 + sr) * ldb + sc;
  const short* pb1 = B + (size_t)(64 + wid * 16 + sr) * ldb + sc;

  for (int k0 = 0; k0 < K; k0 += 32) {
    gload_lds16(pa0 + k0, dA0);
    gload_lds16(pa1 + k0, dA1);
    gload_lds16(pb0 + k0, dB0);
    gload_lds16(pb1 + k0, dB1);
    __syncthreads();
    short8 af[4], bb[4];
#pragma unroll
    for (int m = 0; m < 4; ++m)
      af[m] = *(const short8*)(sA + (wr * 64 + m * 16 + fr) * 32 + fg * 8);
#pragma unroll
    for (int n = 0; n < 4; ++n)
      bb[n] = *(const short8*)(sB + (wc * 64 + n * 16 + fr) * 32 + fg * 8);
#pragma unroll
    for (int m = 0; m < 4; ++m)
#pragma unroll
      for (int n = 0; n < 4; ++n)
        acc[m][n] = __builtin_amdgcn_mfma_f32_16x16x32_bf16(af[m], bb[n], acc[m][n], 0, 0, 0);
    __syncthreads();
  }
}

#define ZERO_ACC4(acc)                       \
  {                                          \
    f32x4 _z = {0.f, 0.f, 0.f, 0.f};         \
    _Pragma("unroll")                        \
    for (int m = 0; m < 4; ++m)              \
      _Pragma("unroll")                      \
      for (int n = 0; n < 4; ++n) acc[m][n] = _z; \
  }

// K1: x (f32) -> xb (bf16), sq[i] = sum x[i]^2. One wave per row.
__global__ __launch_bounds__(256) void k_prep_x(const float* __restrict__ x,
                                                short* __restrict__ xb,
                                                float* __restrict__ sq) {
  const int row  = blockIdx.x * 4 + (threadIdx.x >> 6);
  const int lane = threadIdx.x & 63;
  const float* px = x + (size_t)row * DIM + lane * 8;
  const float4 v0 = *(const float4*)px;
  const float4 v1 = *(const float4*)(px + 4);
  float s = v0.x*v0.x + v0.y*v0.y + v0.z*v0.z + v0.w*v0.w +
            v1.x*v1.x + v1.y*v1.y + v1.z*v1.z + v1.w*v1.w;
  short8 o;
  o[0]=f2bf(v0.x); o[1]=f2bf(v0.y); o[2]=f2bf(v0.z); o[3]=f2bf(v0.w);
  o[4]=f2bf(v1.x); o[5]=f2bf(v1.y); o[6]=f2bf(v1.z); o[7]=f2bf(v1.w);
  *(short8*)(xb + (size_t)row * DIM + lane * 8) = o;
#pragma unroll
  for (int m = 32; m >= 1; m >>= 1) s += __shfl_xor(s, m);
  if (lane == 0) sq[row] = s;
}

// K1b: W (f32) -> Wb (bf16)
__global__ __launch_bounds__(256) void k_prep_w(const float* __restrict__ W,
                                                short* __restrict__ Wb) {
  const int idx = blockIdx.x * 256 + threadIdx.x;
  const float4 v0 = *(const float4*)(W + (size_t)idx * 8);
  const float4 v1 = *(const float4*)(W + (size_t)idx * 8 + 4);
  short8 o;
  o[0]=f2bf(v0.x); o[1]=f2bf(v0.y); o[2]=f2bf(v0.z); o[3]=f2bf(v0.w);
  o[4]=f2bf(v1.x); o[5]=f2bf(v1.y); o[6]=f2bf(v1.z); o[7]=f2bf(v1.w);
  *(short8*)(Wb + (size_t)idx * 8) = o;
}

// K2: YbT[o][i] = bf16( sum_d Wb[o][d] * xb[i][d] )  (Y = x@W.T, transposed)
__global__ __launch_bounds__(256) void k_ybt(const short* __restrict__ xb,
                                             const short* __restrict__ Wb,
                                             short* __restrict__ YbT) {
  __shared__ short smem[8192];
  f32x4 acc[4][4];
  ZERO_ACC4(acc);
  const int rowBase = blockIdx.y * 128;  // o
  const int colBase = blockIdx.x * 128;  // i
  gemm_core_nt(Wb + (size_t)rowBase * DIM, xb + (size_t)colBase * DIM,
               DIM, DIM, DIM, smem, acc);
  const int lane = threadIdx.x & 63, wid = threadIdx.x >> 6;
  const int wr = wid >> 1, wc = wid & 1, fr = lane & 15, fg = lane >> 4;
#pragma unroll
  for (int m = 0; m < 4; ++m)
#pragma unroll
    for (int n = 0; n < 4; ++n)
#pragma unroll
      for (int r = 0; r < 4; ++r) {
        const int ro = rowBase + wr * 64 + m * 16 + fg * 4 + r;
        const int ci = colBase + wc * 64 + n * 16 + fr;
        YbT[(size_t)ro * NPTS + ci] = f2bf(acc[m][n][r]);
      }
}

// K3: P[i][j] = bf16(exp(min(2*dot - si - sj,0)/2048)), rowsum +=, via
// XCD column-band block map + LDS-repack coalesced P stores.
__global__ __launch_bounds__(512, 2) void k_pmat(const short* __restrict__ xb,
                                                 const float* __restrict__ sq,
                                                 short* __restrict__ P,
                                                 float* __restrict__ rowsum,
                                                 int jbase, int SW) {
  __shared__ short lds[65536];   // 128 KiB = 2 buffers x 64 KiB
  f32x4 acc[8][4];
  ZERO_ACC8(acc);
  // XCD band map: xcd = n&7 owns x in [4*xcd, 4*xcd+4) -> its 4 B-panels
  // (1 MB) stay L2-resident; concurrent set ~3 MB < 4 MB L2 per XCD.
  const int n_lin = blockIdx.y * gridDim.x + blockIdx.x;
  const int xcd = n_lin & 7, jj = n_lin >> 3;
  const int bx = (xcd << 2) | (jj & 3);
  const int by = jj >> 2;
  const int rowBase = by * 256;      // i
  const int colTile = bx * 256;      // j within strip
  const int jglob = jbase + colTile;
  gemm256_8ph(xb + (size_t)rowBase * DIM, xb + (size_t)jglob * DIM,
              DIM, DIM, DIM, lds, acc);
  const int lane = threadIdx.x & 63, wid = threadIdx.x >> 6;
  const int tid = threadIdx.x;
  const int wr = wid >> 2, wc = wid & 3, fr = lane & 15, fg = lane >> 4;
  float sj[4];
#pragma unroll
  for (int n = 0; n < 4; ++n) sj[n] = sq[jglob + wc * 64 + n * 16 + fr];
  // epilogue pass 1: exp + rowsum atomics + bf16 into LDS (swizzled repack).
  // After gemm core's final VMB barrier all LDS reads are done block-wide.
#pragma unroll
  for (int m = 0; m < 8; ++m) {
#pragma unroll
    for (int r = 0; r < 4; ++r) {
      const int i = rowBase + wr * 128 + m * 16 + fg * 4 + r;
      const int iloc = wr * 128 + m * 16 + fg * 4 + r;
      const float si = sq[i];
      float rs = 0.f;
#pragma unroll
      for (int nn = 0; nn < 4; ++nn) {
        const float t = fminf(2.f * acc[m][nn][r] - si - sj[nn], 0.f) * (1.0f / 2048.0f);
        const float w = __expf(t);
        rs += w;
        // logical chunk = wc*8 + nn*2 + (fr>>3); phys = chunk ^ ((iloc>>2)&3)
        const int pc = (wc * 8 + nn * 2 + (fr >> 3)) ^ ((iloc >> 2) & 3);
        lds[iloc * 256 + pc * 8 + (fr & 7)] = f2bf(w);
      }
      rs += __shfl_xor(rs, 1);
      rs += __shfl_xor(rs, 2);
      rs += __shfl_xor(rs, 4);
      rs += __shfl_xor(rs, 8);
      if (fr == 0) atomicAdd(&rowsum[i], rs);
    }
  }
  __syncthreads();
  // epilogue pass 2: stream LDS -> P with coalesced short8 stores.
  // 256 rows x 32 chunks = 8192 chunks; 512 threads x 16 iters covers all.
#pragma unroll
  for (int v = 0; v < 16; ++v) {
    const int gc = v * 512 + tid;           // global chunk 0..8191
    const int i = gc >> 5, c = gc & 31;
    const int pc = c ^ ((i >> 2) & 3);
    short8 val = *(const short8*)(lds + i * 256 + pc * 8);
    *(short8*)(P + (size_t)(rowBase + i) * SW + colTile + c * 8) = val;
  }
}

// K4: out_acc[i][o] += sum_j P[i][j] * YbT[o][j]  (z = K-split),
// XCD map: (x,z) fixed per XCD -> 1 MB YbT slice L2-resident.
__global__ __launch_bounds__(512, 2) void k_pv(const short* __restrict__ P,
                                               const short* __restrict__ YbT,
                                               float* __restrict__ out_acc,
                                               int jbase, int SW, int klen,
                                               int nz) {
  __shared__ short lds[65536];   // 128 KiB = 2 buffers x 64 KiB
  f32x4 acc[8][4];
  ZERO_ACC8(acc);
  const int n_lin = (blockIdx.z * gridDim.y + blockIdx.y) * gridDim.x + blockIdx.x;
  int bx, by, bz;
  if (nz == 4) {                 // 2 x * 4 z = 8 -> map to XCD id bits
    bx = n_lin & 1;
    bz = (n_lin >> 1) & 3;
    by = n_lin >> 3;
  } else {
    bx = blockIdx.x; by = blockIdx.y; bz = blockIdx.z;
  }
  const int rowBase = by * 256;  // i
  const int colBase = bx * 256;  // o
  const int kz = bz * klen;
  gemm256_8ph(P + (size_t)rowBase * SW + kz,
              YbT + (size_t)colBase * NPTS + jbase + kz,
              klen, SW, NPTS, lds, acc);
  const int lane = threadIdx.x & 63, wid = threadIdx.x >> 6;
  const int wr = wid >> 2, wc = wid & 3, fr = lane & 15, fg = lane >> 4;
#pragma unroll
  for (int m = 0; m < 8; ++m)
#pragma unroll
    for (int n = 0; n < 4; ++n)
#pragma unroll
      for (int r = 0; r < 4; ++r) {
        const int i = rowBase + wr * 128 + m * 16 + fg * 4 + r;
        const int o = colBase + wc * 64 + n * 16 + fr;
        atomicAdd(&out_acc[(size_t)i * ODIM + o], acc[m][n][r]);
      }
}

// K5: out = out_acc / (rowsum + eps) + b
__global__ __launch_bounds__(256) void k_final(const float* __restrict__ out_acc,
                                               const float* __restrict__ rowsum,
                                               const float* __restrict__ bvec,
                                               float* __restrict__ out) {
  const int idx = blockIdx.x * 256 + threadIdx.x;
  const int i = idx >> 7;
  const int o = (idx & 127) << 2;
  const float inv = 1.f / (rowsum[i] + 1e-8f);
  const float4 a = *(const float4*)(out_acc + (size_t)i * ODIM + o);
  const float4 bb = *(const float4*)(bvec + o);
  float4 r;
  r.x = a.x * inv + bb.x;
  r.y = a.y * inv + bb.y;
  r.z = a.z * inv + bb.z;
  r.w = a.w * inv + bb.w;
  *(float4*)(out + (size_t)i * ODIM + o) = r;
}

extern "C" void kernel_launch(void* const* d_in, const int* in_sizes, int n_in,
                              void* d_out, int out_size, void* d_ws, size_t ws_size,
                              hipStream_t stream) {
  (void)in_sizes; (void)n_in; (void)out_size;
  const float* x = (const float*)d_in[0];
  const float* W = (const float*)d_in[1];
  const float* bvec = (const float*)d_in[2];
  float* out = (float*)d_out;
  char* ws = (char*)d_ws;

  // workspace carving (bytes)
  short* xb      = (short*)(ws + 0);                  //  8 MiB
  short* Wb      = (short*)(ws + 8388608);            //  0.5 MiB
  short* YbT     = (short*)(ws + 8912896);            //  8 MiB
  float* sq      = (float*)(ws + 17301504);           //  32 KiB
  float* rowsum  = (float*)(ws + 17334272);           //  32 KiB
  float* out_acc = (float*)(ws + 17367040);           //  16 MiB
  short* P       = (short*)(ws + 34144256);           //  up to 128 MiB

  // adaptive P-strip width so everything fits in ws (multiples of 256)
  size_t pav = ws_size > 34144256 ? ws_size - 34144256 : 0;
  int SW = 8192;
  while (SW > 256 && (size_t)NPTS * SW * 2 > pav) SW >>= 1;
  const int nstrips = NPTS / SW;
  int ksplit = SW / 2048;
  if (ksplit < 1) ksplit = 1;
  if (ksplit > 4) ksplit = 4;
  const int klen = SW / ksplit;

  hipMemsetAsync(rowsum, 0, NPTS * sizeof(float), stream);
  hipMemsetAsync(out_acc, 0, (size_t)NPTS * ODIM * sizeof(float), stream);

  k_prep_x<<<dim3(NPTS / 4), 256, 0, stream>>>(x, xb, sq);
  k_prep_w<<<dim3(ODIM * DIM / 8 / 256), 256, 0, stream>>>(W, Wb);
  k_ybt<<<dim3(NPTS / 128, ODIM / 128), 256, 0, stream>>>(xb, Wb, YbT);

  for (int s = 0; s < nstrips; ++s) {
    const int jbase = s * SW;
    k_pmat<<<dim3(SW / 256, NPTS / 256), 512, 0, stream>>>(xb, sq, P, rowsum, jbase, SW);
    k_pv<<<dim3(ODIM / 256, NPTS / 256, ksplit), 512, 0, stream>>>(P, YbT, out_acc, jbase, SW, klen, ksplit);
  }

  k_final<<<dim3(NPTS * ODIM / 4 / 256), 256, 0, stream>>>(out_acc, rowsum, bvec, out);
}